// Round 4
// baseline (258.608 us; speedup 1.0000x reference)
//
#include <hip/hip_runtime.h>

// WaveCell: y = denom * (2/dt^2 * y1 - (1/dt^2 - b/dt) * y2 + c^2 * lap(y1))
// denom = 1 / (1/dt^2 + b/dt); lap = 5-point stencil with zero padding, / h^2.
// Outputs: (y, y1) concatenated flat in d_out.
//
// R4: nontemporal LOADS for y2/c/b (no L2-reuse value: y2 streamed once,
//     c/b reuse lives in memory-side L3 which caches regardless of nt) so
//     L2 holds only the y1 row stream -> up/dn halo reads become local-L2
//     hits instead of falling to L3. Keeps R3's XCD-contiguous swizzle +
//     NT stores.

#define WAVE_DT 0.001f
#define WAVE_H  10.0f

typedef float fvec4 __attribute__((ext_vector_type(4)));

__global__ __launch_bounds__(256) void WaveCell_790273982844_kernel(
    const float* __restrict__ c,
    const float* __restrict__ b,
    const float* __restrict__ y1,
    const float* __restrict__ y2,
    float* __restrict__ out_y,
    float* __restrict__ out_y1)
{
    constexpr int W  = 4096;
    constexpr int H  = 4096;
    constexpr int W4 = W / 4;          // 1024 float4 per row

    const float inv_dt2 = 1.0f / (WAVE_DT * WAVE_DT);  // 1e6
    const float inv_dt  = 1.0f / WAVE_DT;              // 1e3
    const float inv_h2  = 1.0f / (WAVE_H * WAVE_H);    // 0.01

    // XCD-contiguous swizzle: hw slot n -> XCD n%8; logical block
    // (n%8)*cpx + n/8 gives XCD k the contiguous band [k*cpx, (k+1)*cpx).
    // nwg = 65536, divisible by 8 -> bijective.
    const unsigned nwg = gridDim.x;
    const unsigned cpx = nwg >> 3;
    const unsigned bid = blockIdx.x;
    const unsigned swz = (bid & 7u) * cpx + (bid >> 3);

    const long t = (long)swz * blockDim.x + threadIdx.x;  // float4 index
    const int  j4      = (int)(t & (W4 - 1));          // column group
    const long rowIdx  = t >> 10;                      // b*H + i
    const int  i       = (int)(rowIdx & (H - 1));      // row within image
    const int  j       = j4 << 2;                      // starting column

    const float* rowC = c  + (long)i * W;
    const float* rowB = b  + (long)i * W;
    const float* row1 = y1 + rowIdx * W;
    const float* row2 = y2 + rowIdx * W;

    const fvec4 zero = (fvec4)0.0f;
    const fvec4 ctr = *(const fvec4*)(row1 + j);
    const fvec4 up  = (i > 0)     ? *(const fvec4*)(row1 - W + j) : zero;
    const fvec4 dn  = (i < H - 1) ? *(const fvec4*)(row1 + W + j) : zero;
    const float lf  = (j > 0)     ? row1[j - 1] : 0.0f;
    const float rt  = (j + 4 < W) ? row1[j + 4] : 0.0f;
    const fvec4 cc  = __builtin_nontemporal_load((const fvec4*)(rowC + j));
    const fvec4 bb  = __builtin_nontemporal_load((const fvec4*)(rowB + j));
    const fvec4 p2  = __builtin_nontemporal_load((const fvec4*)(row2 + j));

    const float le[4] = {lf, ctr.x, ctr.y, ctr.z};
    const float re[4] = {ctr.y, ctr.z, ctr.w, rt};

    fvec4 yo;
#pragma unroll
    for (int k = 0; k < 4; ++k) {
        const float lap   = (up[k] + dn[k] + le[k] + re[k] - 4.0f * ctr[k]) * inv_h2;
        const float bdt   = bb[k] * inv_dt;
        const float denom = 1.0f / (inv_dt2 + bdt);
        yo[k] = denom * (2.0f * inv_dt2 * ctr[k]
                         - (inv_dt2 - bdt) * p2[k]
                         + cc[k] * cc[k] * lap);
    }

    float* o1 = out_y  + rowIdx * W + j;
    float* o2 = out_y1 + rowIdx * W + j;
    __builtin_nontemporal_store(yo,  (fvec4*)o1);
    __builtin_nontemporal_store(ctr, (fvec4*)o2);
}

extern "C" void kernel_launch(void* const* d_in, const int* in_sizes, int n_in,
                              void* d_out, int out_size, void* d_ws, size_t ws_size,
                              hipStream_t stream) {
    (void)in_sizes; (void)n_in; (void)d_ws; (void)ws_size; (void)out_size;

    const float* c  = (const float*)d_in[0];
    const float* b  = (const float*)d_in[1];
    const float* y1 = (const float*)d_in[2];
    const float* y2 = (const float*)d_in[3];

    const long B = 4, H = 4096, W = 4096;
    const long N = B * H * W;                 // 67,108,864 elements per field

    float* out_y  = (float*)d_out;
    float* out_y1 = out_y + N;

    const long totalThreads = N / 4;          // one float4 per thread
    const int  block = 256;
    const long grid  = totalThreads / block;  // 65536

    WaveCell_790273982844_kernel<<<(unsigned)grid, block, 0, stream>>>(
        c, b, y1, y2, out_y, out_y1);
}

// Round 5
// 234.164 us; speedup vs baseline: 1.1044x; 1.1044x over previous
//
#include <hip/hip_runtime.h>

// WaveCell: y = denom * (2/dt^2 * y1 - (1/dt^2 - b/dt) * y2 + c^2 * lap(y1))
// denom = 1 / (1/dt^2 + b/dt); lap = 5-point stencil with zero padding, / h^2.
// Outputs: (y, y1) concatenated flat in d_out.
//
// R5: 2-row vertical coarsening — each thread computes rows (i, i+1) at the
//     same 4-column group. 4 y1-row loads serve 2 output rows (was 3 per
//     row), per-thread MLP doubles, block count halves. Keeps R3's
//     XCD-contiguous swizzle + NT stores; NT LOADS REVERTED (R4 regression:
//     L2-bypass latency > traffic savings).

#define WAVE_DT 0.001f
#define WAVE_H  10.0f

typedef float fvec4 __attribute__((ext_vector_type(4)));

__global__ __launch_bounds__(256) void WaveCell_790273982844_kernel(
    const float* __restrict__ c,
    const float* __restrict__ b,
    const float* __restrict__ y1,
    const float* __restrict__ y2,
    float* __restrict__ out_y,
    float* __restrict__ out_y1)
{
    constexpr int W  = 4096;
    constexpr int H  = 4096;
    constexpr int W4 = W / 4;            // 1024 float4 per row
    constexpr int HP = H / 2;            // 2048 row-pairs per image

    const float inv_dt2 = 1.0f / (WAVE_DT * WAVE_DT);  // 1e6
    const float inv_dt  = 1.0f / WAVE_DT;              // 1e3
    const float inv_h2  = 1.0f / (WAVE_H * WAVE_H);    // 0.01

    // XCD-contiguous bijective swizzle (nwg = 32768, divisible by 8).
    const unsigned nwg = gridDim.x;
    const unsigned cpx = nwg >> 3;
    const unsigned bid = blockIdx.x;
    const unsigned swz = (bid & 7u) * cpx + (bid >> 3);

    const long t       = (long)swz * blockDim.x + threadIdx.x;
    const int  j4      = (int)(t & (W4 - 1));
    const long pairIdx = t >> 10;                    // 0 .. B*HP-1
    const int  ip      = (int)(pairIdx & (HP - 1));  // pair within image
    const long batch   = pairIdx >> 11;              // HP = 2048 -> shift 11
    const int  i       = ip << 1;                    // even row
    const int  j       = j4 << 2;

    const long base = (batch * H + i) * (long)W;     // flat index of row i
    const float* r0 = y1 + base;                     // y1 row i
    const float* r1 = r0 + W;                        // y1 row i+1
    const float* q0 = y2 + base;                     // y2 row i
    const float* c0 = c + (long)i * W;               // c row i
    const float* b0 = b + (long)i * W;               // b row i

    const fvec4 zero = (fvec4)0.0f;
    const fvec4 ym1 = (i > 0)     ? *(const fvec4*)(r0 - W + j) : zero;
    const fvec4 v0  = *(const fvec4*)(r0 + j);
    const fvec4 v1  = *(const fvec4*)(r1 + j);
    const fvec4 yp2 = (i + 2 < H) ? *(const fvec4*)(r1 + W + j) : zero;

    const float lf0 = (j > 0)     ? r0[j - 1] : 0.0f;
    const float rt0 = (j + 4 < W) ? r0[j + 4] : 0.0f;
    const float lf1 = (j > 0)     ? r1[j - 1] : 0.0f;
    const float rt1 = (j + 4 < W) ? r1[j + 4] : 0.0f;

    const fvec4 cc0 = *(const fvec4*)(c0 + j);
    const fvec4 cc1 = *(const fvec4*)(c0 + W + j);
    const fvec4 bb0 = *(const fvec4*)(b0 + j);
    const fvec4 bb1 = *(const fvec4*)(b0 + W + j);
    const fvec4 p20 = *(const fvec4*)(q0 + j);
    const fvec4 p21 = *(const fvec4*)(q0 + W + j);

    const float le0[4] = {lf0, v0.x, v0.y, v0.z};
    const float re0[4] = {v0.y, v0.z, v0.w, rt0};
    const float le1[4] = {lf1, v1.x, v1.y, v1.z};
    const float re1[4] = {v1.y, v1.z, v1.w, rt1};

    fvec4 yo0, yo1;
#pragma unroll
    for (int k = 0; k < 4; ++k) {
        // row i
        {
            const float lap   = (ym1[k] + v1[k] + le0[k] + re0[k] - 4.0f * v0[k]) * inv_h2;
            const float bdt   = bb0[k] * inv_dt;
            const float denom = 1.0f / (inv_dt2 + bdt);
            yo0[k] = denom * (2.0f * inv_dt2 * v0[k]
                              - (inv_dt2 - bdt) * p20[k]
                              + cc0[k] * cc0[k] * lap);
        }
        // row i+1
        {
            const float lap   = (v0[k] + yp2[k] + le1[k] + re1[k] - 4.0f * v1[k]) * inv_h2;
            const float bdt   = bb1[k] * inv_dt;
            const float denom = 1.0f / (inv_dt2 + bdt);
            yo1[k] = denom * (2.0f * inv_dt2 * v1[k]
                              - (inv_dt2 - bdt) * p21[k]
                              + cc1[k] * cc1[k] * lap);
        }
    }

    float* o0 = out_y  + base + j;
    float* o1 = out_y1 + base + j;
    __builtin_nontemporal_store(yo0, (fvec4*)o0);
    __builtin_nontemporal_store(yo1, (fvec4*)(o0 + W));
    __builtin_nontemporal_store(v0,  (fvec4*)o1);
    __builtin_nontemporal_store(v1,  (fvec4*)(o1 + W));
}

extern "C" void kernel_launch(void* const* d_in, const int* in_sizes, int n_in,
                              void* d_out, int out_size, void* d_ws, size_t ws_size,
                              hipStream_t stream) {
    (void)in_sizes; (void)n_in; (void)d_ws; (void)ws_size; (void)out_size;

    const float* c  = (const float*)d_in[0];
    const float* b  = (const float*)d_in[1];
    const float* y1 = (const float*)d_in[2];
    const float* y2 = (const float*)d_in[3];

    const long B = 4, H = 4096, W = 4096;
    const long N = B * H * W;                 // 67,108,864 elements per field

    float* out_y  = (float*)d_out;
    float* out_y1 = out_y + N;

    const long totalThreads = N / 8;          // one (2-row x float4) tile per thread
    const int  block = 256;
    const long grid  = totalThreads / block;  // 32768

    WaveCell_790273982844_kernel<<<(unsigned)grid, block, 0, stream>>>(
        c, b, y1, y2, out_y, out_y1);
}